// Round 7
// baseline (458.552 us; speedup 1.0000x reference)
//
#include <hip/hip_runtime.h>
#include <math.h>

#define NB 4
#define HH 180
#define WWW 180
#define SPATIAL (HH*WWW)     // 32400
#define CH_HID 170
#define CLAMP_ROW (SPATIAL-2)
#define SLAB 8192            // v4 elements per reduce-A block (128KB lidar)
#define CHUNKB 128           // voxels per reduce-B block

typedef short v8s __attribute__((ext_vector_type(8)));
typedef short v4s __attribute__((ext_vector_type(4)));
typedef float v4f __attribute__((ext_vector_type(4)));

__device__ __forceinline__ unsigned short f2bf(float f) {
    unsigned u = __float_as_uint(f);
    u += 0x7FFFu + ((u >> 16) & 1);
    return (unsigned short)(u >> 16);
}
__device__ __forceinline__ v4f vmin4(v4f a, v4f b) {
    v4f r; r[0]=fminf(a[0],b[0]); r[1]=fminf(a[1],b[1]); r[2]=fminf(a[2],b[2]); r[3]=fminf(a[3],b[3]); return r;
}
__device__ __forceinline__ v4f vmax4(v4f a, v4f b) {
    v4f r; r[0]=fmaxf(a[0],b[0]); r[1]=fmaxf(a[1],b[1]); r[2]=fmaxf(a[2],b[2]); r[3]=fmaxf(a[3],b[3]); return r;
}

// ==== k1: fused prep (W swizzle) + setup (img transpose) + reduce-A (lidar minmax) ====
// blocks [0,64): prep; [64, 64+4052): setup; [64+4052, +nblkA): reduceA.
// All three are mutually independent (disjoint inputs/outputs).
__global__ __launch_bounds__(256)
void k1(const float* __restrict__ Wf1, const float* __restrict__ Wf2,
        unsigned short* __restrict__ W1S, unsigned short* __restrict__ W2S,
        const float* __restrict__ img, float* __restrict__ camT,
        const float* __restrict__ lidar, const int* __restrict__ bidx,
        float* __restrict__ pA, int N, int nsetup, int nblkA) {
    __shared__ __align__(16) char sm[32768];
    const int tid = threadIdx.x;
    const int bx = blockIdx.x;

    if (bx < 64) {
        // ---------- prep: swizzle Wf1/Wf2 [k][n] fp32 -> MFMA-fragment bf16 ----------
        const int net = bx >> 5, xb = bx & 31;
        const float* W = net ? Wf2 : Wf1;
        unsigned short* WS = net ? W2S : W1S;
        const int frag = xb * 4 + (tid >> 6);   // 0..127 = nt*8+ks
        const int lane = tid & 63;
        const int nt = frag >> 3, ks = frag & 7;
        const int q = lane >> 4, ml = lane & 15;
        v8s pk;
        #pragma unroll
        for (int j = 0; j < 8; ++j)
            pk[j] = (short)f2bf(W[(ks*32 + q*8 + j)*256 + nt*16 + ml]);
        *(v8s*)&WS[(frag*64 + lane)*8] = pk;
    } else if (bx < 64 + nsetup) {
        // ---------- setup: transpose img batch 0 [128][32400] -> camT [32400][128] ----------
        float (*tile)[33] = (float(*)[33])sm;   // 32*33*4 = 4.2KB
        const int bs = bx - 64;
        const int sx = bs % 1013, sy = bs / 1013;
        int s0 = sx * 32, c0 = sy * 32;
        int lx = tid & 31, ly = tid >> 5;
        for (int i = 0; i < 4; ++i) {
            int s = s0 + lx;
            if (s < SPATIAL)
                tile[ly + i*8][lx] = img[(c0 + ly + i*8) * SPATIAL + s];
        }
        __syncthreads();
        for (int i = 0; i < 4; ++i) {
            int s = s0 + ly + i*8;
            if (s < SPATIAL)
                camT[s*128 + c0 + lx] = tile[lx][ly + i*8];
        }
    } else {
        // ---------- reduce-A: lidar min/max over 4 batches, contiguous slab ----------
        v4f (*red)[8][32] = (v4f(*)[8][32])sm;     // 32KB
        const int ba = bx - 64 - nsetup;
        const int total = N * 32;                  // v4 elements
        const int beg = ba * SLAB;
        const int end = min(beg + SLAB, total);
        const v4f pinf = {INFINITY, INFINITY, INFINITY, INFINITY};
        const v4f ninf = {-INFINITY, -INFINITY, -INFINITY, -INFINITY};
        v4f mn0 = pinf, mn1 = pinf, mn2 = pinf, mn3 = pinf;
        v4f mx0 = ninf, mx1 = ninf, mx2 = ninf, mx3 = ninf;

        #define ACCUM(vv, bb) do { \
            bool m0_ = ((bb) == 0), m1_ = ((bb) == 1), m2_ = ((bb) == 2), m3_ = ((bb) == 3); \
            mn0 = m0_ ? vmin4(mn0, (vv)) : mn0;  mx0 = m0_ ? vmax4(mx0, (vv)) : mx0; \
            mn1 = m1_ ? vmin4(mn1, (vv)) : mn1;  mx1 = m1_ ? vmax4(mx1, (vv)) : mx1; \
            mn2 = m2_ ? vmin4(mn2, (vv)) : mn2;  mx2 = m2_ ? vmax4(mx2, (vv)) : mx2; \
            mn3 = m3_ ? vmin4(mn3, (vv)) : mn3;  mx3 = m3_ ? vmax4(mx3, (vv)) : mx3; \
        } while (0)

        int i = beg + tid;
        for (; i + 768 < end; i += 1024) {
            v4f x0 = *(const v4f*)&lidar[(size_t)i * 4];
            v4f x1 = *(const v4f*)&lidar[(size_t)(i + 256) * 4];
            v4f x2 = *(const v4f*)&lidar[(size_t)(i + 512) * 4];
            v4f x3 = *(const v4f*)&lidar[(size_t)(i + 768) * 4];
            int b0 = bidx[i >> 5];
            int b1 = bidx[(i + 256) >> 5];
            int b2 = bidx[(i + 512) >> 5];
            int b3 = bidx[(i + 768) >> 5];
            ACCUM(x0, b0); ACCUM(x1, b1); ACCUM(x2, b2); ACCUM(x3, b3);
        }
        for (; i < end; i += 256) {
            v4f x = *(const v4f*)&lidar[(size_t)i * 4];
            int b = bidx[i >> 5];
            ACCUM(x, b);
        }
        #undef ACCUM

        const int sub = tid >> 5, cc = tid & 31;
        red[sub][0][cc] = mn0; red[sub][1][cc] = mx0;
        red[sub][2][cc] = mn1; red[sub][3][cc] = mx1;
        red[sub][4][cc] = mn2; red[sub][5][cc] = mx2;
        red[sub][6][cc] = mn3; red[sub][7][cc] = mx3;
        __syncthreads();
        const int acc = tid >> 5;        // acc = (b<<1)|ismax
        const bool ismax = acc & 1;
        v4f r = red[0][acc][cc];
        #pragma unroll
        for (int s = 1; s < 8; ++s)
            r = ismax ? vmax4(r, red[s][acc][cc]) : vmin4(r, red[s][acc][cc]);
        *(v4f*)&pA[((size_t)ba * 8 + acc) * 128 + cc * 4] = r;
    }
}

// ==== k2: fused reduce-B (batch-0 camT gather minmax) + fin-A (lidar partials -> statsf) ====
// blocks [0, nblkB): reduceB; [nblkB, nblkB+32): finA.
// (batch>=1 cam stats are the single CLAMP_ROW row due to the faithful clamp bug -> k_mlp.)
__global__ __launch_bounds__(256)
void k2(const float* __restrict__ camT,
        const int* __restrict__ bidx, const int* __restrict__ yidx,
        const int* __restrict__ xidx,
        const float* __restrict__ pA, float* __restrict__ pB,
        float* __restrict__ statsf, int N, int nblkA, int nblkB) {
    __shared__ __align__(16) char sm[12288];
    const int tid = threadIdx.x;
    const int bx = blockIdx.x;

    if (bx < nblkB) {
        // ---------- reduce-B ----------
        int* srow = (int*)sm;                              // 512B
        v4f (*cred)[2][32] = (v4f(*)[2][32])(sm + 2048);   // 8KB
        const int vbeg = bx * CHUNKB;
        const int cnt = min(CHUNKB, N - vbeg);
        const bool active = (cnt > 0) && (bidx[vbeg] == 0);  // sorted batch_idx
        if (!active) {
            int a2 = tid >> 7, ch = tid & 127;
            pB[((size_t)bx * 2 + a2) * 128 + ch] = a2 ? -INFINITY : INFINITY;
            return;
        }
        if (tid < cnt) {
            int v = vbeg + tid;
            srow[tid] = (bidx[v] == 0) ? min(yidx[v] * WWW + xidx[v], CLAMP_ROW) : -1;
        }
        __syncthreads();
        const int c4 = (tid & 31) * 4;
        v4f mn = {INFINITY, INFINITY, INFINITY, INFINITY};
        v4f mx = {-INFINITY, -INFINITY, -INFINITY, -INFINITY};
        for (int idx = tid >> 5; idx < cnt; idx += 8) {
            int r = srow[idx];
            if (r >= 0) {
                v4f v = *(const v4f*)&camT[(size_t)r * 128 + c4];
                mn = vmin4(mn, v);
                mx = vmax4(mx, v);
            }
        }
        const int sub = tid >> 5, cc = tid & 31;
        cred[sub][0][cc] = mn;
        cred[sub][1][cc] = mx;
        __syncthreads();
        if (tid < 64) {
            const bool ismax = tid >= 32;
            v4f r = cred[0][ismax][cc];
            #pragma unroll
            for (int s = 1; s < 8; ++s)
                r = ismax ? vmax4(r, cred[s][ismax][cc]) : vmin4(r, cred[s][ismax][cc]);
            *(v4f*)&pB[((size_t)bx * 2 + (ismax ? 1 : 0)) * 128 + cc * 4] = r;
        }
    } else {
        // ---------- fin-A: reduce pA[nblkA][8][128] -> statsf lidar sections ----------
        float (*red2)[33] = (float(*)[33])sm;
        const int bf = bx - nblkB;            // 0..31
        const int g = tid >> 5, l = tid & 31;
        const int acc = bf >> 2;              // (b<<1)|ismax
        const int quarter = bf & 3;
        const int ch = quarter * 32 + l;
        const bool ismax = (acc & 1) != 0;
        const float* base = pA + acc * 128 + ch;

        float r = ismax ? -INFINITY : INFINITY;
        int row = g;
        for (; row + 24 < nblkA; row += 32) {
            float a = base[(size_t)row * 1024];
            float b = base[(size_t)(row + 8) * 1024];
            float c = base[(size_t)(row + 16) * 1024];
            float d = base[(size_t)(row + 24) * 1024];
            if (ismax) r = fmaxf(fmaxf(r, a), fmaxf(fmaxf(b, c), d));
            else       r = fminf(fminf(r, a), fminf(fminf(b, c), d));
        }
        for (; row < nblkA; row += 8) {
            float a = base[(size_t)row * 1024];
            r = ismax ? fmaxf(r, a) : fminf(r, a);
        }
        red2[g][l] = r;
        __syncthreads();
        if (tid < 32) {
            float v = red2[0][l];
            #pragma unroll
            for (int s = 1; s < 8; ++s)
                v = ismax ? fmaxf(v, red2[s][l]) : fminf(v, red2[s][l]);
            int bb = acc >> 1;
            statsf[bb * 512 + (acc & 1) * 128 + ch] = v;
        }
    }
}

// ==== k_mlp: tiny attention MLPs, block = (batch, net) ====
// lidar stats from statsf; cam b==0 stats reduced inline from pB;
// cam b>=1 stats = camT[CLAMP_ROW] (clamp bug: min==max==that row).
__global__ void k_mlp(const float* __restrict__ statsf, const float* __restrict__ pB,
                      const float* __restrict__ camT,
                      const float* __restrict__ Wl1, const float* __restrict__ Wl2,
                      const float* __restrict__ Wc1, const float* __restrict__ Wc2,
                      float* __restrict__ att, int nblkB) {
    __shared__ float cat[512];
    __shared__ float hid[CH_HID];
    int b = blockIdx.x >> 1;
    int net = blockIdx.x & 1;
    const float* W1 = net ? Wc1 : Wl1;
    const float* W2 = net ? Wc2 : Wl2;
    int tid = threadIdx.x;
    for (int j = tid; j < 512; j += 256) {
        float x;
        if (j < 256) {
            x = statsf[b * 512 + j];
        } else if (b == 0) {
            const bool ismax = (j >= 384);
            const int ch = j & 127;
            const float* base = pB + (ismax ? 128 : 0) + ch;
            float r = ismax ? -INFINITY : INFINITY;
            int row = 0;
            for (; row + 3 < nblkB; row += 4) {
                float a = base[(size_t)row * 256];
                float c1 = base[(size_t)(row + 1) * 256];
                float c2 = base[(size_t)(row + 2) * 256];
                float c3 = base[(size_t)(row + 3) * 256];
                if (ismax) r = fmaxf(fmaxf(r, a), fmaxf(fmaxf(c1, c2), c3));
                else       r = fminf(fminf(r, a), fminf(fminf(c1, c2), c3));
            }
            for (; row < nblkB; ++row) {
                float a = base[(size_t)row * 256];
                r = ismax ? fmaxf(r, a) : fminf(r, a);
            }
            x = r;
        } else {
            x = camT[(size_t)CLAMP_ROW * 128 + (j & 127)];
        }
        cat[j] = x;
    }
    __syncthreads();
    if (tid < CH_HID) {
        float s = 0.f;
        #pragma unroll 16
        for (int k = 0; k < 512; ++k) s += cat[k] * W1[k*CH_HID + tid];
        hid[tid] = fmaxf(s, 0.f);
    }
    __syncthreads();
    if (tid < 128) {
        float s = 0.f;
        #pragma unroll 10
        for (int k = 0; k < CH_HID; ++k) s += hid[k] * W2[k*128 + tid];
        s = fmaxf(s, 0.f);
        att[b*256 + net*128 + tid] = 1.f / (1.f + expf(-s));
    }
}

// ==== k_main: gate -> [64,256]bf16 tile -> MFMA MLP, swizzled-B, vec stores ====
__global__ __launch_bounds__(256, 3)
void k_main(const float* __restrict__ lidar, const float* __restrict__ camT,
            const int* __restrict__ bidx, const int* __restrict__ yidx,
            const int* __restrict__ xidx, const float* __restrict__ att,
            const unsigned short* __restrict__ W1S, const unsigned short* __restrict__ W2S,
            float* __restrict__ out, int N) {
    __shared__ __align__(16) char smem[64 * 264 * 2];          // 33.8 KB, dual-use
    unsigned short (*sA)[264] = (unsigned short(*)[264])smem;  // bf16 A tile, +8 pad
    float* sAf = (float*)smem;                                  // fp32 out staging, stride 260
    __shared__ int srow[64];
    __shared__ int sbb[64];
    const int tid = threadIdx.x;
    const int v0 = blockIdx.x * 64;

    if (tid < 64) {
        int v = v0 + tid;
        int b = 0, row = 0;
        if (v < N) {
            b = bidx[v];
            row = min(b*SPATIAL + yidx[v]*WWW + xidx[v], CLAMP_ROW);
        }
        sbb[tid] = b;
        srow[tid] = row;
    }
    const int c = (tid & 63) * 4;
    const bool cam = (c >= 128);
    v4f attv0 = *(const v4f*)&att[0*256 + c];
    v4f attv1 = *(const v4f*)&att[1*256 + c];
    v4f attv2 = *(const v4f*)&att[2*256 + c];
    v4f attv3 = *(const v4f*)&att[3*256 + c];
    __syncthreads();

    // prologue: 2 rounds of 8 prefetched float4 loads -> gate -> bf16 -> sA
    #pragma unroll
    for (int half = 0; half < 2; ++half) {
        v4f x[8]; int bm[8];
        #pragma unroll
        for (int j = 0; j < 8; ++j) {
            int m = (half*8 + j)*4 + (tid >> 6);
            int vc = min(v0 + m, N - 1);
            bm[j] = sbb[m];
            const float* src = cam ? &camT[(size_t)srow[m]*128 + (c - 128)]
                                   : &lidar[(size_t)vc*128 + c];
            x[j] = *(const v4f*)src;
        }
        #pragma unroll
        for (int j = 0; j < 8; ++j) {
            int m = (half*8 + j)*4 + (tid >> 6);
            int b = bm[j];
            v4f a = attv0;
            if (b == 1) a = attv1;
            if (b == 2) a = attv2;
            if (b == 3) a = attv3;
            v4f val = x[j] * a;
            v4s pk;
            #pragma unroll
            for (int jj = 0; jj < 4; ++jj) pk[jj] = (short)f2bf(val[jj]);
            *(v4s*)&sA[m][c] = pk;
        }
    }

    const int wave = tid >> 6;
    const int lane = tid & 63;
    const int ml = lane & 15;
    const int q = lane >> 4;

    v4f acc[4][4];
    for (int layer = 0; layer < 2; ++layer) {
        const unsigned short* WS = layer ? W2S : W1S;
        const v4f zz = {0.f, 0.f, 0.f, 0.f};
        for (int rt = 0; rt < 4; ++rt)
            for (int ct = 0; ct < 4; ++ct) acc[rt][ct] = zz;

        __syncthreads();   // sA ready
        #pragma unroll
        for (int ks = 0; ks < 8; ++ks) {
            v8s a[4];
            const int ka = ks*32 + q*8;
            #pragma unroll
            for (int rt = 0; rt < 4; ++rt)
                a[rt] = *(const v8s*)&sA[rt*16 + ml][ka];
            #pragma unroll
            for (int ct = 0; ct < 4; ++ct) {
                // swizzled layout: one contiguous 1KB burst per wave
                v8s bfr = *(const v8s*)&WS[(((wave*4 + ct)*8 + ks)*64 + lane)*8];
                #pragma unroll
                for (int rt = 0; rt < 4; ++rt)
                    acc[rt][ct] = __builtin_amdgcn_mfma_f32_16x16x32_bf16(
                        a[rt], bfr, acc[rt][ct], 0, 0, 0);
            }
        }
        __syncthreads();   // all sA reads done
        if (layer == 0) {
            // C/D layout: col = lane&15, row = q*4 + reg
            for (int rt = 0; rt < 4; ++rt)
                for (int ct = 0; ct < 4; ++ct)
                    for (int r = 0; r < 4; ++r)
                        sA[rt*16 + q*4 + r][wave*64 + ct*16 + ml] =
                            f2bf(fmaxf(acc[rt][ct][r], 0.f));
        }
    }

    // epilogue: two 32-row passes through LDS (fp32, stride 260: 2-way banks = free),
    // then fully-coalesced float4 stores
    const int c4 = (tid & 63) * 4;
    #pragma unroll
    for (int p = 0; p < 2; ++p) {
        __syncthreads();
        #pragma unroll
        for (int rt = 2*p; rt < 2*p + 2; ++rt)
            for (int ct = 0; ct < 4; ++ct)
                for (int r = 0; r < 4; ++r)
                    sAf[((rt - 2*p)*16 + q*4 + r)*260 + wave*64 + ct*16 + ml] =
                        fmaxf(acc[rt][ct][r], 0.f);
        __syncthreads();
        #pragma unroll
        for (int i = 0; i < 8; ++i) {
            int rl = (tid >> 6) + i*4;      // 0..31
            int v = v0 + p*32 + rl;
            if (v < N)
                *(v4f*)&out[(size_t)v*256 + c4] = *(const v4f*)&sAf[rl*260 + c4];
        }
    }
}

extern "C" void kernel_launch(void* const* d_in, const int* in_sizes, int n_in,
                              void* d_out, int out_size, void* d_ws, size_t ws_size,
                              hipStream_t stream) {
    const float* lidar = (const float*)d_in[0];
    const float* img   = (const float*)d_in[1];
    const int*   bidx  = (const int*)d_in[2];
    const int*   yidx  = (const int*)d_in[3];
    const int*   xidx  = (const int*)d_in[4];
    const float* Wl1   = (const float*)d_in[5];
    const float* Wl2   = (const float*)d_in[6];
    const float* Wc1   = (const float*)d_in[7];
    const float* Wc2   = (const float*)d_in[8];
    const float* Wf1   = (const float*)d_in[9];
    const float* Wf2   = (const float*)d_in[10];
    float* out = (float*)d_out;
    const int N = in_sizes[0] / 128;

    // ws: [statsf 8KB][att 4KB][pad to 16KB][W1S 128KB][W2S 128KB][camT 16.6MB][pA][pB]
    float* statsf = (float*)d_ws;
    float* att = (float*)((char*)d_ws + 8192);
    unsigned short* W1S = (unsigned short*)((char*)d_ws + 16384);
    unsigned short* W2S = (unsigned short*)((char*)d_ws + 16384 + 131072);
    float* camT = (float*)((char*)d_ws + 16384 + 262144);

    const int nsetup = ((SPATIAL + 31) / 32) * 4;          // 4052
    const int nblkA = (N * 32 + SLAB - 1) / SLAB;          // 625 at N=160000
    const int nblkB = (N + CHUNKB - 1) / CHUNKB;           // 1250
    const size_t pA_bytes = (size_t)nblkA * 8 * 128 * 4;
    const size_t pB_bytes = (size_t)nblkB * 2 * 128 * 4;
    const size_t pA_off = 16384 + 262144 + (size_t)SPATIAL * 128 * 4;  // after camT
    float *pA, *pB;
    if (ws_size >= pA_off + pA_bytes + pB_bytes) {
        pA = (float*)((char*)d_ws + pA_off);
    } else {
        // carve scratch from the tail of out: k_main overwrites it afterward (stream-ordered)
        size_t off = ((size_t)out_size - (pA_bytes + pB_bytes)) & ~(size_t)255;
        pA = (float*)((char*)out + off);
    }
    pB = (float*)((char*)pA + pA_bytes);

    k1<<<64 + nsetup + nblkA, 256, 0, stream>>>(Wf1, Wf2, W1S, W2S, img, camT,
                                                lidar, bidx, pA, N, nsetup, nblkA);
    k2<<<nblkB + 32, 256, 0, stream>>>(camT, bidx, yidx, xidx, pA, pB, statsf, N, nblkA, nblkB);
    k_mlp<<<8, 256, 0, stream>>>(statsf, pB, camT, Wl1, Wl2, Wc1, Wc2, att, nblkB);
    k_main<<<(N + 63) / 64, 256, 0, stream>>>(lidar, camT, bidx, yidx, xidx, att, W1S, W2S, out, N);
}

// Round 8
// 392.057 us; speedup vs baseline: 1.1696x; 1.1696x over previous
//
#include <hip/hip_runtime.h>
#include <math.h>

#define NB 4
#define HH 180
#define WWW 180
#define SPATIAL (HH*WWW)     // 32400
#define CH_HID 170
#define CLAMP_ROW (SPATIAL-2)
#define SLAB 8192            // v4 elements per reduce-A block (128KB lidar)
#define CHUNKB 128           // voxels per reduce-B block

typedef short v8s __attribute__((ext_vector_type(8)));
typedef short v4s __attribute__((ext_vector_type(4)));
typedef float v4f __attribute__((ext_vector_type(4)));

__device__ __forceinline__ unsigned short f2bf(float f) {
    unsigned u = __float_as_uint(f);
    u += 0x7FFFu + ((u >> 16) & 1);
    return (unsigned short)(u >> 16);
}
__device__ __forceinline__ v4f vmin4(v4f a, v4f b) {
    v4f r; r[0]=fminf(a[0],b[0]); r[1]=fminf(a[1],b[1]); r[2]=fminf(a[2],b[2]); r[3]=fminf(a[3],b[3]); return r;
}
__device__ __forceinline__ v4f vmax4(v4f a, v4f b) {
    v4f r; r[0]=fmaxf(a[0],b[0]); r[1]=fmaxf(a[1],b[1]); r[2]=fmaxf(a[2],b[2]); r[3]=fmaxf(a[3],b[3]); return r;
}

// ==== k1: fused prep (W swizzle) + setup (img transpose) + reduce-A (lidar minmax) ====
// blocks [0,64): prep; [64, 64+4052): setup; [64+4052, +nblkA): reduceA.
// All three are mutually independent (disjoint inputs/outputs).
__global__ __launch_bounds__(256)
void k1(const float* __restrict__ Wf1, const float* __restrict__ Wf2,
        unsigned short* __restrict__ W1S, unsigned short* __restrict__ W2S,
        const float* __restrict__ img, float* __restrict__ camT,
        const float* __restrict__ lidar, const int* __restrict__ bidx,
        float* __restrict__ pA, int N, int nsetup, int nblkA) {
    __shared__ __align__(16) char sm[32768];
    const int tid = threadIdx.x;
    const int bx = blockIdx.x;

    if (bx < 64) {
        // ---------- prep: swizzle Wf1/Wf2 [k][n] fp32 -> MFMA-fragment bf16 ----------
        const int net = bx >> 5, xb = bx & 31;
        const float* W = net ? Wf2 : Wf1;
        unsigned short* WS = net ? W2S : W1S;
        const int frag = xb * 4 + (tid >> 6);   // 0..127 = nt*8+ks
        const int lane = tid & 63;
        const int nt = frag >> 3, ks = frag & 7;
        const int q = lane >> 4, ml = lane & 15;
        v8s pk;
        #pragma unroll
        for (int j = 0; j < 8; ++j)
            pk[j] = (short)f2bf(W[(ks*32 + q*8 + j)*256 + nt*16 + ml]);
        *(v8s*)&WS[(frag*64 + lane)*8] = pk;
    } else if (bx < 64 + nsetup) {
        // ---------- setup: transpose img batch 0 [128][32400] -> camT [32400][128] ----------
        float (*tile)[33] = (float(*)[33])sm;   // 32*33*4 = 4.2KB
        const int bs = bx - 64;
        const int sx = bs % 1013, sy = bs / 1013;
        int s0 = sx * 32, c0 = sy * 32;
        int lx = tid & 31, ly = tid >> 5;
        for (int i = 0; i < 4; ++i) {
            int s = s0 + lx;
            if (s < SPATIAL)
                tile[ly + i*8][lx] = img[(c0 + ly + i*8) * SPATIAL + s];
        }
        __syncthreads();
        for (int i = 0; i < 4; ++i) {
            int s = s0 + ly + i*8;
            if (s < SPATIAL)
                camT[s*128 + c0 + lx] = tile[lx][ly + i*8];
        }
    } else {
        // ---------- reduce-A: lidar min/max over 4 batches, contiguous slab ----------
        v4f (*red)[8][32] = (v4f(*)[8][32])sm;     // 32KB
        const int ba = bx - 64 - nsetup;
        const int total = N * 32;                  // v4 elements
        const int beg = ba * SLAB;
        const int end = min(beg + SLAB, total);
        const v4f pinf = {INFINITY, INFINITY, INFINITY, INFINITY};
        const v4f ninf = {-INFINITY, -INFINITY, -INFINITY, -INFINITY};
        v4f mn0 = pinf, mn1 = pinf, mn2 = pinf, mn3 = pinf;
        v4f mx0 = ninf, mx1 = ninf, mx2 = ninf, mx3 = ninf;

        #define ACCUM(vv, bb) do { \
            bool m0_ = ((bb) == 0), m1_ = ((bb) == 1), m2_ = ((bb) == 2), m3_ = ((bb) == 3); \
            mn0 = m0_ ? vmin4(mn0, (vv)) : mn0;  mx0 = m0_ ? vmax4(mx0, (vv)) : mx0; \
            mn1 = m1_ ? vmin4(mn1, (vv)) : mn1;  mx1 = m1_ ? vmax4(mx1, (vv)) : mx1; \
            mn2 = m2_ ? vmin4(mn2, (vv)) : mn2;  mx2 = m2_ ? vmax4(mx2, (vv)) : mx2; \
            mn3 = m3_ ? vmin4(mn3, (vv)) : mn3;  mx3 = m3_ ? vmax4(mx3, (vv)) : mx3; \
        } while (0)

        int i = beg + tid;
        for (; i + 768 < end; i += 1024) {
            v4f x0 = *(const v4f*)&lidar[(size_t)i * 4];
            v4f x1 = *(const v4f*)&lidar[(size_t)(i + 256) * 4];
            v4f x2 = *(const v4f*)&lidar[(size_t)(i + 512) * 4];
            v4f x3 = *(const v4f*)&lidar[(size_t)(i + 768) * 4];
            int b0 = bidx[i >> 5];
            int b1 = bidx[(i + 256) >> 5];
            int b2 = bidx[(i + 512) >> 5];
            int b3 = bidx[(i + 768) >> 5];
            ACCUM(x0, b0); ACCUM(x1, b1); ACCUM(x2, b2); ACCUM(x3, b3);
        }
        for (; i < end; i += 256) {
            v4f x = *(const v4f*)&lidar[(size_t)i * 4];
            int b = bidx[i >> 5];
            ACCUM(x, b);
        }
        #undef ACCUM

        const int sub = tid >> 5, cc = tid & 31;
        red[sub][0][cc] = mn0; red[sub][1][cc] = mx0;
        red[sub][2][cc] = mn1; red[sub][3][cc] = mx1;
        red[sub][4][cc] = mn2; red[sub][5][cc] = mx2;
        red[sub][6][cc] = mn3; red[sub][7][cc] = mx3;
        __syncthreads();
        const int acc = tid >> 5;        // acc = (b<<1)|ismax
        const bool ismax = acc & 1;
        v4f r = red[0][acc][cc];
        #pragma unroll
        for (int s = 1; s < 8; ++s)
            r = ismax ? vmax4(r, red[s][acc][cc]) : vmin4(r, red[s][acc][cc]);
        *(v4f*)&pA[((size_t)ba * 8 + acc) * 128 + cc * 4] = r;
    }
}

// ==== k2: fused reduce-B (batch-0 camT gather minmax) + fin-A (lidar partials -> statsf) ====
// blocks [0, nblkB): reduceB; [nblkB, nblkB+32): finA.
// (batch>=1 cam stats are the single CLAMP_ROW row due to the faithful clamp bug -> k_mlp.)
__global__ __launch_bounds__(256)
void k2(const float* __restrict__ camT,
        const int* __restrict__ bidx, const int* __restrict__ yidx,
        const int* __restrict__ xidx,
        const float* __restrict__ pA, float* __restrict__ pB,
        float* __restrict__ statsf, int N, int nblkA, int nblkB) {
    __shared__ __align__(16) char sm[12288];
    const int tid = threadIdx.x;
    const int bx = blockIdx.x;

    if (bx < nblkB) {
        // ---------- reduce-B ----------
        int* srow = (int*)sm;                              // 512B
        v4f (*cred)[2][32] = (v4f(*)[2][32])(sm + 2048);   // 8KB
        const int vbeg = bx * CHUNKB;
        const int cnt = min(CHUNKB, N - vbeg);
        const bool active = (cnt > 0) && (bidx[vbeg] == 0);  // sorted batch_idx
        if (!active) {
            int a2 = tid >> 7, ch = tid & 127;
            pB[((size_t)bx * 2 + a2) * 128 + ch] = a2 ? -INFINITY : INFINITY;
            return;
        }
        if (tid < cnt) {
            int v = vbeg + tid;
            srow[tid] = (bidx[v] == 0) ? min(yidx[v] * WWW + xidx[v], CLAMP_ROW) : -1;
        }
        __syncthreads();
        const int c4 = (tid & 31) * 4;
        v4f mn = {INFINITY, INFINITY, INFINITY, INFINITY};
        v4f mx = {-INFINITY, -INFINITY, -INFINITY, -INFINITY};
        for (int idx = tid >> 5; idx < cnt; idx += 8) {
            int r = srow[idx];
            if (r >= 0) {
                v4f v = *(const v4f*)&camT[(size_t)r * 128 + c4];
                mn = vmin4(mn, v);
                mx = vmax4(mx, v);
            }
        }
        const int sub = tid >> 5, cc = tid & 31;
        cred[sub][0][cc] = mn;
        cred[sub][1][cc] = mx;
        __syncthreads();
        if (tid < 64) {
            const bool ismax = tid >= 32;
            v4f r = cred[0][ismax][cc];
            #pragma unroll
            for (int s = 1; s < 8; ++s)
                r = ismax ? vmax4(r, cred[s][ismax][cc]) : vmin4(r, cred[s][ismax][cc]);
            *(v4f*)&pB[((size_t)bx * 2 + (ismax ? 1 : 0)) * 128 + cc * 4] = r;
        }
    } else {
        // ---------- fin-A: reduce pA[nblkA][8][128] -> statsf lidar sections ----------
        float (*red2)[33] = (float(*)[33])sm;
        const int bf = bx - nblkB;            // 0..31
        const int g = tid >> 5, l = tid & 31;
        const int acc = bf >> 2;              // (b<<1)|ismax
        const int quarter = bf & 3;
        const int ch = quarter * 32 + l;
        const bool ismax = (acc & 1) != 0;
        const float* base = pA + acc * 128 + ch;

        float r = ismax ? -INFINITY : INFINITY;
        int row = g;
        for (; row + 24 < nblkA; row += 32) {
            float a = base[(size_t)row * 1024];
            float b = base[(size_t)(row + 8) * 1024];
            float c = base[(size_t)(row + 16) * 1024];
            float d = base[(size_t)(row + 24) * 1024];
            if (ismax) r = fmaxf(fmaxf(r, a), fmaxf(fmaxf(b, c), d));
            else       r = fminf(fminf(r, a), fminf(fminf(b, c), d));
        }
        for (; row < nblkA; row += 8) {
            float a = base[(size_t)row * 1024];
            r = ismax ? fmaxf(r, a) : fminf(r, a);
        }
        red2[g][l] = r;
        __syncthreads();
        if (tid < 32) {
            float v = red2[0][l];
            #pragma unroll
            for (int s = 1; s < 8; ++s)
                v = ismax ? fmaxf(v, red2[s][l]) : fminf(v, red2[s][l]);
            int bb = acc >> 1;
            statsf[bb * 512 + (acc & 1) * 128 + ch] = v;
        }
    }
}

// ==== k_finB: reduce pB[nblkB][2][128] -> statsf cam batch-0 section ====
// 8 blocks: acc = bx>>2 (0 min / 1 max), quarter = bx&3; 8-way row-parallel.
__global__ __launch_bounds__(256)
void k_finB(const float* __restrict__ pB, float* __restrict__ statsf, int nblkB) {
    __shared__ float red2[8][33];
    const int bx = blockIdx.x, tid = threadIdx.x;
    const int g = tid >> 5, l = tid & 31;
    const int acc = bx >> 2;
    const int quarter = bx & 3;
    const int ch = quarter * 32 + l;
    const bool ismax = (acc == 1);
    const float* base = pB + acc * 128 + ch;

    float r = ismax ? -INFINITY : INFINITY;
    int row = g;
    for (; row + 24 < nblkB; row += 32) {
        float a = base[(size_t)row * 256];
        float b = base[(size_t)(row + 8) * 256];
        float c = base[(size_t)(row + 16) * 256];
        float d = base[(size_t)(row + 24) * 256];
        if (ismax) r = fmaxf(fmaxf(r, a), fmaxf(fmaxf(b, c), d));
        else       r = fminf(fminf(r, a), fminf(fminf(b, c), d));
    }
    for (; row < nblkB; row += 8) {
        float a = base[(size_t)row * 256];
        r = ismax ? fmaxf(r, a) : fminf(r, a);
    }
    red2[g][l] = r;
    __syncthreads();
    if (tid < 32) {
        float v = red2[0][l];
        #pragma unroll
        for (int s = 1; s < 8; ++s)
            v = ismax ? fmaxf(v, red2[s][l]) : fminf(v, red2[s][l]);
        statsf[256 + acc * 128 + ch] = v;   // batch-0 cam section
    }
}

// ==== k_mlp: tiny attention MLPs, block = (batch, net) ====
// cam stats for batch>=1 come straight from camT[CLAMP_ROW] (clamp bug: min==max==row).
__global__ void k_mlp(const float* __restrict__ statsf, const float* __restrict__ camT,
                      const float* __restrict__ Wl1, const float* __restrict__ Wl2,
                      const float* __restrict__ Wc1, const float* __restrict__ Wc2,
                      float* __restrict__ att) {
    __shared__ float cat[512];
    __shared__ float hid[CH_HID];
    int b = blockIdx.x >> 1;
    int net = blockIdx.x & 1;
    const float* W1 = net ? Wc1 : Wl1;
    const float* W2 = net ? Wc2 : Wl2;
    int tid = threadIdx.x;
    for (int j = tid; j < 512; j += 256) {
        float x;
        if (j < 256 || b == 0) x = statsf[b * 512 + j];
        else                   x = camT[(size_t)CLAMP_ROW * 128 + (j & 127)];
        cat[j] = x;
    }
    __syncthreads();
    if (tid < CH_HID) {
        float s = 0.f;
        #pragma unroll 16
        for (int k = 0; k < 512; ++k) s += cat[k] * W1[k*CH_HID + tid];
        hid[tid] = fmaxf(s, 0.f);
    }
    __syncthreads();
    if (tid < 128) {
        float s = 0.f;
        #pragma unroll 10
        for (int k = 0; k < CH_HID; ++k) s += hid[k] * W2[k*128 + tid];
        s = fmaxf(s, 0.f);
        att[b*256 + net*128 + tid] = 1.f / (1.f + expf(-s));
    }
}

// ==== k_main: gate -> [64,256]bf16 tile -> MFMA MLP, swizzled-B, vec stores ====
__global__ __launch_bounds__(256, 3)
void k_main(const float* __restrict__ lidar, const float* __restrict__ camT,
            const int* __restrict__ bidx, const int* __restrict__ yidx,
            const int* __restrict__ xidx, const float* __restrict__ att,
            const unsigned short* __restrict__ W1S, const unsigned short* __restrict__ W2S,
            float* __restrict__ out, int N) {
    __shared__ __align__(16) char smem[64 * 264 * 2];          // 33.8 KB, dual-use
    unsigned short (*sA)[264] = (unsigned short(*)[264])smem;  // bf16 A tile, +8 pad
    float* sAf = (float*)smem;                                  // fp32 out staging, stride 260
    __shared__ int srow[64];
    __shared__ int sbb[64];
    const int tid = threadIdx.x;
    const int v0 = blockIdx.x * 64;

    if (tid < 64) {
        int v = v0 + tid;
        int b = 0, row = 0;
        if (v < N) {
            b = bidx[v];
            row = min(b*SPATIAL + yidx[v]*WWW + xidx[v], CLAMP_ROW);
        }
        sbb[tid] = b;
        srow[tid] = row;
    }
    const int c = (tid & 63) * 4;
    const bool cam = (c >= 128);
    v4f attv0 = *(const v4f*)&att[0*256 + c];
    v4f attv1 = *(const v4f*)&att[1*256 + c];
    v4f attv2 = *(const v4f*)&att[2*256 + c];
    v4f attv3 = *(const v4f*)&att[3*256 + c];
    __syncthreads();

    // prologue: 2 rounds of 8 prefetched float4 loads -> gate -> bf16 -> sA
    #pragma unroll
    for (int half = 0; half < 2; ++half) {
        v4f x[8]; int bm[8];
        #pragma unroll
        for (int j = 0; j < 8; ++j) {
            int m = (half*8 + j)*4 + (tid >> 6);
            int vc = min(v0 + m, N - 1);
            bm[j] = sbb[m];
            const float* src = cam ? &camT[(size_t)srow[m]*128 + (c - 128)]
                                   : &lidar[(size_t)vc*128 + c];
            x[j] = *(const v4f*)src;
        }
        #pragma unroll
        for (int j = 0; j < 8; ++j) {
            int m = (half*8 + j)*4 + (tid >> 6);
            int b = bm[j];
            v4f a = attv0;
            if (b == 1) a = attv1;
            if (b == 2) a = attv2;
            if (b == 3) a = attv3;
            v4f val = x[j] * a;
            v4s pk;
            #pragma unroll
            for (int jj = 0; jj < 4; ++jj) pk[jj] = (short)f2bf(val[jj]);
            *(v4s*)&sA[m][c] = pk;
        }
    }

    const int wave = tid >> 6;
    const int lane = tid & 63;
    const int ml = lane & 15;
    const int q = lane >> 4;

    v4f acc[4][4];
    for (int layer = 0; layer < 2; ++layer) {
        const unsigned short* WS = layer ? W2S : W1S;
        const v4f zz = {0.f, 0.f, 0.f, 0.f};
        for (int rt = 0; rt < 4; ++rt)
            for (int ct = 0; ct < 4; ++ct) acc[rt][ct] = zz;

        __syncthreads();   // sA ready
        #pragma unroll
        for (int ks = 0; ks < 8; ++ks) {
            v8s a[4];
            const int ka = ks*32 + q*8;
            #pragma unroll
            for (int rt = 0; rt < 4; ++rt)
                a[rt] = *(const v8s*)&sA[rt*16 + ml][ka];
            #pragma unroll
            for (int ct = 0; ct < 4; ++ct) {
                // swizzled layout: one contiguous 1KB burst per wave
                v8s bfr = *(const v8s*)&WS[(((wave*4 + ct)*8 + ks)*64 + lane)*8];
                #pragma unroll
                for (int rt = 0; rt < 4; ++rt)
                    acc[rt][ct] = __builtin_amdgcn_mfma_f32_16x16x32_bf16(
                        a[rt], bfr, acc[rt][ct], 0, 0, 0);
            }
        }
        __syncthreads();   // all sA reads done
        if (layer == 0) {
            // C/D layout: col = lane&15, row = q*4 + reg
            for (int rt = 0; rt < 4; ++rt)
                for (int ct = 0; ct < 4; ++ct)
                    for (int r = 0; r < 4; ++r)
                        sA[rt*16 + q*4 + r][wave*64 + ct*16 + ml] =
                            f2bf(fmaxf(acc[rt][ct][r], 0.f));
        }
    }

    // epilogue: two 32-row passes through LDS (fp32, stride 260: 2-way banks = free),
    // then fully-coalesced float4 stores
    const int c4 = (tid & 63) * 4;
    #pragma unroll
    for (int p = 0; p < 2; ++p) {
        __syncthreads();
        #pragma unroll
        for (int rt = 2*p; rt < 2*p + 2; ++rt)
            for (int ct = 0; ct < 4; ++ct)
                for (int r = 0; r < 4; ++r)
                    sAf[((rt - 2*p)*16 + q*4 + r)*260 + wave*64 + ct*16 + ml] =
                        fmaxf(acc[rt][ct][r], 0.f);
        __syncthreads();
        #pragma unroll
        for (int i = 0; i < 8; ++i) {
            int rl = (tid >> 6) + i*4;      // 0..31
            int v = v0 + p*32 + rl;
            if (v < N)
                *(v4f*)&out[(size_t)v*256 + c4] = *(const v4f*)&sAf[rl*260 + c4];
        }
    }
}

extern "C" void kernel_launch(void* const* d_in, const int* in_sizes, int n_in,
                              void* d_out, int out_size, void* d_ws, size_t ws_size,
                              hipStream_t stream) {
    const float* lidar = (const float*)d_in[0];
    const float* img   = (const float*)d_in[1];
    const int*   bidx  = (const int*)d_in[2];
    const int*   yidx  = (const int*)d_in[3];
    const int*   xidx  = (const int*)d_in[4];
    const float* Wl1   = (const float*)d_in[5];
    const float* Wl2   = (const float*)d_in[6];
    const float* Wc1   = (const float*)d_in[7];
    const float* Wc2   = (const float*)d_in[8];
    const float* Wf1   = (const float*)d_in[9];
    const float* Wf2   = (const float*)d_in[10];
    float* out = (float*)d_out;
    const int N = in_sizes[0] / 128;

    // ws: [statsf 8KB][att 4KB][pad to 16KB][W1S 128KB][W2S 128KB][camT 16.6MB][pA][pB]
    float* statsf = (float*)d_ws;
    float* att = (float*)((char*)d_ws + 8192);
    unsigned short* W1S = (unsigned short*)((char*)d_ws + 16384);
    unsigned short* W2S = (unsigned short*)((char*)d_ws + 16384 + 131072);
    float* camT = (float*)((char*)d_ws + 16384 + 262144);

    const int nsetup = ((SPATIAL + 31) / 32) * 4;          // 4052
    const int nblkA = (N * 32 + SLAB - 1) / SLAB;          // 625 at N=160000
    const int nblkB = (N + CHUNKB - 1) / CHUNKB;           // 1250
    const size_t pA_bytes = (size_t)nblkA * 8 * 128 * 4;
    const size_t pB_bytes = (size_t)nblkB * 2 * 128 * 4;
    const size_t pA_off = 16384 + 262144 + (size_t)SPATIAL * 128 * 4;  // after camT
    float *pA, *pB;
    if (ws_size >= pA_off + pA_bytes + pB_bytes) {
        pA = (float*)((char*)d_ws + pA_off);
    } else {
        // carve scratch from the tail of out: k_main overwrites it afterward (stream-ordered)
        size_t off = ((size_t)out_size - (pA_bytes + pB_bytes)) & ~(size_t)255;
        pA = (float*)((char*)out + off);
    }
    pB = (float*)((char*)pA + pA_bytes);

    k1<<<64 + nsetup + nblkA, 256, 0, stream>>>(Wf1, Wf2, W1S, W2S, img, camT,
                                                lidar, bidx, pA, N, nsetup, nblkA);
    k2<<<nblkB + 32, 256, 0, stream>>>(camT, bidx, yidx, xidx, pA, pB, statsf, N, nblkA, nblkB);
    k_finB<<<8, 256, 0, stream>>>(pB, statsf, nblkB);
    k_mlp<<<8, 256, 0, stream>>>(statsf, camT, Wl1, Wl2, Wc1, Wc2, att);
    k_main<<<(N + 63) / 64, 256, 0, stream>>>(lidar, camT, bidx, yidx, xidx, att, W1S, W2S, out, N);
}